// Round 5
// baseline (68.869 us; speedup 1.0000x reference)
//
#include <hip/hip_runtime.h>
#include <stdint.h>

typedef __bf16 bf16x8 __attribute__((ext_vector_type(8)));
typedef float  f32x4  __attribute__((ext_vector_type(4)));
typedef float  f32x16 __attribute__((ext_vector_type(16)));

#define NB 8
#define NT 2048
#define NC 1024
#define NH 64

#define WSWZ_BYTES (32 * 12 * 64 * 8 * 2)   // 384 KB swizzled W frags
#define QK_BYTES   (NB * NT * NH * 2)       // 2 MB each for Q, K, V^T (bf16)

// 32x32 attention: QBLK=32 (q-tiles 0..63/batch), KVBLK=64, segments of 2 steps.
// Per batch: sum over qt of ceil(nkt/2) = 544.
#define SEG_PER_B 544
#define SLOTS     (NB * SEG_PER_B)          // 4352
#define PO_OFF    (WSWZ_BYTES + 3 * QK_BYTES)
#define PO_BYTES  (SLOTS * 32 * 64 * 2)     // bf16 partial O, [slot][q32][d64]
#define PM_OFF    (PO_OFF + PO_BYTES)
#define PM_BYTES  (SLOTS * 32 * 4)
#define PL_OFF    (PM_OFF + PM_BYTES)

#define SOFTMAX_SC 0.18033688011112042f     // 0.125 * log2(e)
#define MASK_VAL  (-30000.0f)               // safe-range sentinel
#define MINIT_VAL (-10000.0f)

// ---------------------------------------------------------------------------
__device__ __forceinline__ unsigned cvtpk(float lo, float hi) {
  unsigned r;
  asm("v_cvt_pk_bf16_f32 %0, %1, %2" : "=v"(r) : "v"(lo), "v"(hi));
  return r;
}
__device__ __forceinline__ bf16x8 cvt8(float4 f0, float4 f1) {
  bf16x8 h;
  h[0] = (__bf16)f0.x; h[1] = (__bf16)f0.y; h[2] = (__bf16)f0.z; h[3] = (__bf16)f0.w;
  h[4] = (__bf16)f1.x; h[5] = (__bf16)f1.y; h[6] = (__bf16)f1.z; h[7] = (__bf16)f1.w;
  return h;
}

// ---------------------------------------------------------------------------
// Kernel 0: swizzle concat(Wq,Wk,Wv) [1024][192] f32 -> bf16 MFMA B-fragments.
__global__ __launch_bounds__(64) void sdpa_prep_w(
    const float* __restrict__ Wq, const float* __restrict__ Wk,
    const float* __restrict__ Wv, __bf16* __restrict__ wswz) {
  const int blk = blockIdx.x;            // 384 = 32 kb * 12 nf
  const int kb = blk / 12, nf = blk % 12;
  const int l = threadIdx.x;
  const float* W = (nf < 4) ? Wq : ((nf < 8) ? Wk : Wv);
  const int col = ((nf & 3) << 4) + (l & 15);
  const int c0 = kb * 32 + ((l >> 4) << 3);
  union { __bf16 h[8]; uint4 u; } pk;
#pragma unroll
  for (int j = 0; j < 8; ++j) pk.h[j] = (__bf16)W[(size_t)(c0 + j) * NH + col];
  *reinterpret_cast<uint4*>(wswz + ((size_t)blk * 64 + l) * 8) = pk.u;
}

// ---------------------------------------------------------------------------
// Kernel 1: QKV projection, zero-LDS-staging. 1 wave per block, BM=16,
// grid 1024. A-frags loaded directly from row-major x (2x float4 + cvt);
// B-frags from wswz (L1/L2-hot). Pipeline: A 2 steps ahead, B 1 ahead.
#define LDB(KS, DST) do {                                                     \
    const __bf16* wp_ = wswz + (size_t)(KS) * 6144 + (size_t)l * 8;           \
    _Pragma("unroll")                                                         \
    for (int n_ = 0; n_ < 12; ++n_)                                           \
      DST[n_] = *reinterpret_cast<const bf16x8*>(wp_ + n_ * 512);             \
  } while (0)

__global__ __launch_bounds__(64) void sdpa_qkv(
    const float* __restrict__ x, const __bf16* __restrict__ wswz,
    __bf16* __restrict__ Qb, __bf16* __restrict__ Kb, __bf16* __restrict__ VTb) {
  __shared__ __attribute__((aligned(16))) __bf16 vt[64 * 24];  // V^T transpose
  const int l = threadIdx.x;
  const int r0 = blockIdx.x * 16;        // global row base (0..16368)
  const int arow = l & 15, kseg = l >> 4;
  const float* xp = x + (size_t)(r0 + arow) * NC + kseg * 8;

  f32x4 acc[12];
#pragma unroll
  for (int n = 0; n < 12; ++n) acc[n] = f32x4{0.f, 0.f, 0.f, 0.f};

  // A slots: slotA = step 2it, slotB = step 2it+1 (each 8 floats)
  float4 aA0 = *reinterpret_cast<const float4*>(xp);
  float4 aA1 = *reinterpret_cast<const float4*>(xp + 4);
  float4 aB0 = *reinterpret_cast<const float4*>(xp + 32);
  float4 aB1 = *reinterpret_cast<const float4*>(xp + 36);
  bf16x8 BfA[12], BfB[12];
  LDB(0, BfA);

  for (int it = 0; it < 16; ++it) {
    const int ks = 2 * it;
    // ---- phase 0: step ks (A=slotA, B=BfA) ----
    {
      const bf16x8 a = cvt8(aA0, aA1);
      const int k2 = (ks + 2 <= 31) ? ks + 2 : 31;
      aA0 = *reinterpret_cast<const float4*>(xp + k2 * 32);
      aA1 = *reinterpret_cast<const float4*>(xp + k2 * 32 + 4);
      const int kb = (ks + 1 <= 31) ? ks + 1 : 31;
      LDB(kb, BfB);
#pragma unroll
      for (int n = 0; n < 12; ++n)
        acc[n] = __builtin_amdgcn_mfma_f32_16x16x32_bf16(a, BfA[n], acc[n], 0, 0, 0);
    }
    // ---- phase 1: step ks+1 (A=slotB, B=BfB) ----
    {
      const bf16x8 a = cvt8(aB0, aB1);
      const int k3 = (ks + 3 <= 31) ? ks + 3 : 31;
      aB0 = *reinterpret_cast<const float4*>(xp + k3 * 32);
      aB1 = *reinterpret_cast<const float4*>(xp + k3 * 32 + 4);
      const int kb = (ks + 2 <= 31) ? ks + 2 : 31;
      LDB(kb, BfA);
#pragma unroll
      for (int n = 0; n < 12; ++n)
        acc[n] = __builtin_amdgcn_mfma_f32_16x16x32_bf16(a, BfB[n], acc[n], 0, 0, 0);
    }
  }

  // Epilogue. C-layout: col = l&15, row = (l>>4)*4 + r.
  const int batch = r0 >> 11;
  const int t0 = r0 & (NT - 1);
  const int ccol = l & 15, crow4 = (l >> 4) << 2;
#pragma unroll
  for (int n16 = 0; n16 < 8; ++n16) {
    __bf16* dst = (n16 < 4) ? Qb : Kb;
    const int col = ((n16 & 3) << 4) + ccol;
#pragma unroll
    for (int r = 0; r < 4; ++r)
      dst[(size_t)(r0 + crow4 + r) * NH + col] = (__bf16)acc[n16][r];
  }
#pragma unroll
  for (int n16 = 8; n16 < 12; ++n16) {
    const int d = ((n16 - 8) << 4) + ccol;
#pragma unroll
    for (int r = 0; r < 4; ++r)
      vt[d * 24 + crow4 + r] = (__bf16)acc[n16][r];
  }
  __syncthreads();                        // single wave: trivial
  {
    const uint4 v0 = *reinterpret_cast<const uint4*>(vt + l * 24);
    const uint4 v1 = *reinterpret_cast<const uint4*>(vt + l * 24 + 8);
    __bf16* dst = VTb + (size_t)(batch * 64 + l) * NT + t0;
    *reinterpret_cast<uint4*>(dst) = v0;
    *reinterpret_cast<uint4*>(dst + 8) = v1;
  }
}

// ---------------------------------------------------------------------------
// Kernel 2: attention segment, 32x32 MFMA, swapped QK^T (S^T = K Q^T), all
// softmax + P-layout conversion in registers (no LDS, no barriers).
// D-layout (32x32): col=l&31, row=(r&3)+8*(r>>2)+4*(l>>5). Segment = 2 tiles.
__global__ __launch_bounds__(64) void sdpa_attn_seg(
    const __bf16* __restrict__ Qb, const __bf16* __restrict__ Kb,
    const __bf16* __restrict__ VTb, __bf16* __restrict__ po,
    float* __restrict__ pm, float* __restrict__ pl) {
  const int l = threadIdx.x;
  const int bid = blockIdx.x;
  const int b = bid & 7;                  // XCD-pinned batch
  const int s = bid >> 3;
  // slot -> (qt, seg): qts grouped by m = qt>>1 (nkt = m+1, cnt = ceil((m+1)/2))
  int m = 0, base = 0;
  while (true) {
    const int c = (m + 2) & ~1;           // 2 * ceil((m+1)/2)
    if (s < base + c) break;
    base += c; ++m;
  }
  const int rem = s - base;
  const int cnt = (m + 2) >> 1;
  const int qt = 2 * m + (rem >= cnt ? 1 : 0);
  const int seg = rem - (rem >= cnt ? cnt : 0);
  const int nkt = m + 1;
  const int ndiag = nkt - 1;
  const int kt0 = seg * 2;
  const int kt1 = (kt0 + 2 < nkt) ? (kt0 + 2) : nkt;

  const __bf16* Qp = Qb + (size_t)b * NT * NH;
  const __bf16* Kp = Kb + (size_t)b * NT * NH;
  const __bf16* Vp = VTb + (size_t)b * NH * NT;
  const int lq = l & 31, hi = l >> 5;
  const int q0 = qt * 32;
  const int qa = q0 + lq;

  bf16x8 qf[4];
#pragma unroll
  for (int ks = 0; ks < 4; ++ks)
    qf[ks] = *reinterpret_cast<const bf16x8*>(Qp + (size_t)(q0 + lq) * NH + ks * 16 + hi * 8);

  f32x16 o0 = {}, o1 = {};
  float mreg = MINIT_VAL, lsum = 0.f;

  bf16x8 kc[8], kn[8], vv[8];
#pragma unroll
  for (int t = 0; t < 2; ++t)
#pragma unroll
    for (int ks = 0; ks < 4; ++ks)
      kc[t * 4 + ks] = *reinterpret_cast<const bf16x8*>(
          Kp + (size_t)(kt0 * 64 + 32 * t + lq) * NH + ks * 16 + hi * 8);

  for (int kt = kt0; kt < kt1; ++kt) {
    // V loads issued first; consumed after softmax (latency hidden)
#pragma unroll
    for (int dt = 0; dt < 2; ++dt)
#pragma unroll
      for (int ks = 0; ks < 4; ++ks)
        vv[dt * 4 + ks] = *reinterpret_cast<const bf16x8*>(
            Vp + (size_t)(32 * dt + lq) * NT + kt * 64 + ks * 16 + hi * 8);

    f32x16 s0 = {}, s1 = {};
    __builtin_amdgcn_s_setprio(1);
#pragma unroll
    for (int ks = 0; ks < 4; ++ks)
      s0 = __builtin_amdgcn_mfma_f32_32x32x16_bf16(kc[ks], qf[ks], s0, 0, 0, 0);
#pragma unroll
    for (int ks = 0; ks < 4; ++ks)
      s1 = __builtin_amdgcn_mfma_f32_32x32x16_bf16(kc[4 + ks], qf[ks], s1, 0, 0, 0);
    __builtin_amdgcn_s_setprio(0);

    const bool more = (kt + 1 < kt1);
    if (more) {                            // prefetch next K tile
#pragma unroll
      for (int t = 0; t < 2; ++t)
#pragma unroll
        for (int ks = 0; ks < 4; ++ks)
          kn[t * 4 + ks] = *reinterpret_cast<const bf16x8*>(
              Kp + (size_t)((kt + 1) * 64 + 32 * t + lq) * NH + ks * 16 + hi * 8);
    }

    if (kt == ndiag) {                     // causal mask (safe sentinel)
#pragma unroll
      for (int r = 0; r < 16; ++r) {
        const int kvr = kt * 64 + (r & 3) + 8 * (r >> 2) + 4 * hi;
        if (kvr > qa) s0[r] = MASK_VAL;
        if (kvr + 32 > qa) s1[r] = MASK_VAL;
      }
    }

    // row max: in-register tree over own 16, then cross-half shfl
    float t16[16];
#pragma unroll
    for (int r = 0; r < 16; ++r) t16[r] = fmaxf(s0[r], s1[r]);
#pragma unroll
    for (int wdt = 8; wdt > 0; wdt >>= 1)
#pragma unroll
      for (int r = 0; r < 16; ++r) if (r < wdt) t16[r] = fmaxf(t16[r], t16[r + wdt]);
    const float pmax = fmaxf(t16[0], __shfl_xor(t16[0], 32));
    const float mn = fmaxf(mreg, pmax);
    const float esc = exp2f(fminf((mreg - mn) * SOFTMAX_SC, 0.f));
    const float msc = mn * SOFTMAX_SC;
    mreg = mn;
#pragma unroll
    for (int r = 0; r < 16; ++r)
      s0[r] = exp2f(fminf(fmaf(s0[r], SOFTMAX_SC, -msc), 0.f));
#pragma unroll
    for (int r = 0; r < 16; ++r)
      s1[r] = exp2f(fminf(fmaf(s1[r], SOFTMAX_SC, -msc), 0.f));
#pragma unroll
    for (int r = 0; r < 16; ++r) t16[r] = s0[r] + s1[r];
#pragma unroll
    for (int wdt = 8; wdt > 0; wdt >>= 1)
#pragma unroll
      for (int r = 0; r < 16; ++r) if (r < wdt) t16[r] += t16[r + wdt];
    const float rs = t16[0] + __shfl_xor(t16[0], 32);
    lsum = lsum * esc + rs;
    o0 *= esc; o1 *= esc;

    // P^T (D-layout f32) -> B-fragments, direction-proof cross-half routing.
    __builtin_amdgcn_s_setprio(1);
#pragma unroll
    for (int ks16 = 0; ks16 < 4; ++ks16) {
      const f32x16& pt = (ks16 < 2) ? s0 : s1;
      const int base8 = 8 * (ks16 & 1);
      const unsigned w0 = cvtpk(pt[base8 + 0], pt[base8 + 1]);
      const unsigned w1 = cvtpk(pt[base8 + 2], pt[base8 + 3]);
      const unsigned w2 = cvtpk(pt[base8 + 4], pt[base8 + 5]);
      const unsigned w3 = cvtpk(pt[base8 + 6], pt[base8 + 7]);
      const unsigned m_a = hi ? w0 : w2;
      const unsigned m_b = hi ? w1 : w3;
      const unsigned e_a = __shfl_xor(m_a, 32);
      const unsigned e_b = __shfl_xor(m_b, 32);
      union { unsigned u[4]; bf16x8 v; } pb;
      pb.u[0] = hi ? e_a : w0;
      pb.u[1] = hi ? e_b : w1;
      pb.u[2] = hi ? w2 : e_a;
      pb.u[3] = hi ? w3 : e_b;
      o0 = __builtin_amdgcn_mfma_f32_32x32x16_bf16(vv[ks16], pb.v, o0, 0, 0, 0);
      o1 = __builtin_amdgcn_mfma_f32_32x32x16_bf16(vv[4 + ks16], pb.v, o1, 0, 0, 0);
    }
    __builtin_amdgcn_s_setprio(0);

    if (more) {
#pragma unroll
      for (int i = 0; i < 8; ++i) kc[i] = kn[i];
    }
  }

  // write partials: po[slot][q 32][d 64] bf16 (unnormalized), pm/pl per row
  const int slot = b * SEG_PER_B + s;
  __bf16* pop = po + (size_t)slot * 2048;
#pragma unroll
  for (int dt = 0; dt < 2; ++dt) {
    const f32x16& ov = dt ? o1 : o0;
#pragma unroll
    for (int u = 0; u < 4; ++u) {
      uint2 val;
      val.x = cvtpk(ov[4 * u + 0], ov[4 * u + 1]);
      val.y = cvtpk(ov[4 * u + 2], ov[4 * u + 3]);
      *reinterpret_cast<uint2*>(pop + lq * 64 + 8 * u + 4 * hi + 32 * dt) = val;
    }
  }
  if (hi == 0) {
    pm[slot * 32 + lq] = mreg;
    pl[slot * 32 + lq] = lsum;
  }
}

// ---------------------------------------------------------------------------
// Kernel 3: combine <=16 segments per q-tile (32 rows), normalize, f32 out.
__global__ __launch_bounds__(256) void sdpa_combine(
    const __bf16* __restrict__ po, const float* __restrict__ pm,
    const float* __restrict__ pl, float* __restrict__ out) {
  const int bid = blockIdx.x;              // 512: (qt<<3) | b
  const int b = bid & 7, qt = bid >> 3;
  const int mg = qt >> 1;
  int base = 0;
  for (int mm = 0; mm < mg; ++mm) base += (mm + 2) & ~1;
  const int cnt = (mg + 2) >> 1;
  base += (qt & 1) ? cnt : 0;
  const int nseg = cnt;                    // ceil(nkt/2), nkt = mg+1
  const int sbase = b * SEG_PER_B + base;
  const int t = threadIdx.x;
  const int r = t >> 3, dc = (t & 7) << 3;

  float M = MASK_VAL;
  for (int s = 0; s < nseg; ++s) M = fmaxf(M, pm[(sbase + s) * 32 + r]);
  float L = 0.f;
  float acc[8] = {0.f, 0.f, 0.f, 0.f, 0.f, 0.f, 0.f, 0.f};
  for (int s = 0; s < nseg; ++s) {
    const int slot = sbase + s;
    const float w = exp2f(fminf((pm[slot * 32 + r] - M) * SOFTMAX_SC, 0.f));
    L += pl[slot * 32 + r] * w;
    const bf16x8 v = *reinterpret_cast<const bf16x8*>(po + (size_t)slot * 2048 + r * 64 + dc);
#pragma unroll
    for (int j = 0; j < 8; ++j) acc[j] += w * (float)v[j];
  }
  const float inv = 1.f / L;
  float4 v0 = {acc[0] * inv, acc[1] * inv, acc[2] * inv, acc[3] * inv};
  float4 v1 = {acc[4] * inv, acc[5] * inv, acc[6] * inv, acc[7] * inv};
  float* dst = out + ((size_t)b * NT + qt * 32 + r) * NH + dc;
  *reinterpret_cast<float4*>(dst) = v0;
  *reinterpret_cast<float4*>(dst + 4) = v1;
}

// ---------------------------------------------------------------------------
extern "C" void kernel_launch(void* const* d_in, const int* in_sizes, int n_in,
                              void* d_out, int out_size, void* d_ws, size_t ws_size,
                              hipStream_t stream) {
  const float* x  = (const float*)d_in[0];
  const float* Wq = (const float*)d_in[1];
  const float* Wk = (const float*)d_in[2];
  const float* Wv = (const float*)d_in[3];
  char* ws = (char*)d_ws;
  __bf16* wswz = (__bf16*)(ws);
  __bf16* Qb   = (__bf16*)(ws + WSWZ_BYTES);
  __bf16* Kb   = (__bf16*)(ws + WSWZ_BYTES + QK_BYTES);
  __bf16* VTb  = (__bf16*)(ws + WSWZ_BYTES + 2 * (size_t)QK_BYTES);
  __bf16* po   = (__bf16*)(ws + PO_OFF);
  float*  pm   = (float*)(ws + PM_OFF);
  float*  pl   = (float*)(ws + PL_OFF);
  float* out = (float*)d_out;

  sdpa_prep_w<<<dim3(384), dim3(64), 0, stream>>>(Wq, Wk, Wv, wswz);
  sdpa_qkv<<<dim3(1024), dim3(64), 0, stream>>>(x, wswz, Qb, Kb, VTb);
  sdpa_attn_seg<<<dim3(SLOTS), dim3(64), 0, stream>>>(Qb, Kb, VTb, po, pm, pl);
  sdpa_combine<<<dim3(NB * 64), dim3(256), 0, stream>>>(po, pm, pl, out);
}